// Round 9
// baseline (86.742 us; speedup 1.0000x reference)
//
#include <hip/hip_runtime.h>
#include <math.h>

#define HW   3136   // 56*56
#define NC   512    // channels
#define NB   32     // batch
#define KSEL 256    // top-k

typedef float f32x4 __attribute__((ext_vector_type(4)));

// ---------------------------------------------------------------------------
// Kernel 1: per-(b,c) mean+max over HW; desc = mean + max (conv is linear,
// no bias, so conv(avg)+conv(mx) == conv(avg+mx)). TWO rows per wave for
// doubled load ILP (24 outstanding f32x4/lane); 2048 blocks x 256 threads.
// Plain loads so x allocates in L2/L3 -> gather re-reads hit Infinity Cache.
// ---------------------------------------------------------------------------
__global__ __launch_bounds__(256) void reduce_mean_max(
    const float* __restrict__ x, float* __restrict__ desc)
{
    const int wid  = threadIdx.x >> 6;      // 0..3
    const int lane = threadIdx.x & 63;
    const int row0 = blockIdx.x * 8 + wid * 2;   // 2048 blocks * 8 rows

    const f32x4* p0 = (const f32x4*)(x + (size_t)row0 * HW);
    const f32x4* p1 = (const f32x4*)(x + (size_t)(row0 + 1) * HW);

    float s0 = 0.0f, m0 = -INFINITY, s1 = 0.0f, m1 = -INFINITY;
#pragma unroll
    for (int i = 0; i < 12; ++i) {          // 12*64 = 768 float4 per row
        f32x4 a = p0[lane + i * 64];
        f32x4 b = p1[lane + i * 64];
        s0 += (a.x + a.y) + (a.z + a.w);
        m0 = fmaxf(m0, fmaxf(fmaxf(a.x, a.y), fmaxf(a.z, a.w)));
        s1 += (b.x + b.y) + (b.z + b.w);
        m1 = fmaxf(m1, fmaxf(fmaxf(b.x, b.y), fmaxf(b.z, b.w)));
    }
    if (lane < 16) {                        // tail: 784-768
        f32x4 a = p0[lane + 768];
        f32x4 b = p1[lane + 768];
        s0 += (a.x + a.y) + (a.z + a.w);
        m0 = fmaxf(m0, fmaxf(fmaxf(a.x, a.y), fmaxf(a.z, a.w)));
        s1 += (b.x + b.y) + (b.z + b.w);
        m1 = fmaxf(m1, fmaxf(fmaxf(b.x, b.y), fmaxf(b.z, b.w)));
    }
#pragma unroll
    for (int off = 32; off; off >>= 1) {
        s0 += __shfl_down(s0, off, 64);
        m0 = fmaxf(m0, __shfl_down(m0, off, 64));
        s1 += __shfl_down(s1, off, 64);
        m1 = fmaxf(m1, __shfl_down(m1, off, 64));
    }
    if (lane == 0) {
        desc[row0]     = s0 * (1.0f / (float)HW) + m0;
        desc[row0 + 1] = s1 * (1.0f / (float)HW) + m1;
    }
}

// ---------------------------------------------------------------------------
// Kernel 2: fused top-k + gather. 1024 blocks x 256 threads; 32 blocks per
// batch, each handling 8 (b,k) pairs. Every block REDUNDANTLY recomputes its
// batch's conv1d+sigmoid+top-K from desc (identical deterministic fp32
// sequence in all blocks -> identical selection, no cross-block comms),
// keeps the (idx,val) list in LDS, then gathers its 8 channels.
// Ascending-channel compaction == reference's argsort(idx) re-sort.
// ---------------------------------------------------------------------------
__global__ __launch_bounds__(256) void topk_gather(
    const float* __restrict__ x, const float* __restrict__ w,
    const float* __restrict__ desc, float* __restrict__ out)
{
    const int tid   = threadIdx.x;
    const int b     = blockIdx.x >> 5;       // 32 blocks per batch
    const int kbase = (blockIdx.x & 31) * 8;

    __shared__ float s_d[NC + 2];
    __shared__ float s_score[NC];
    __shared__ int   s_wcnt[8];
    __shared__ int   s_idx[KSEL];
    __shared__ float s_sv[KSEL];

    // ---- per-batch scores (thread t owns channels t and t+256) ----
    if (tid == 0) { s_d[0] = 0.0f; s_d[NC + 1] = 0.0f; }
    s_d[tid + 1]   = desc[b * NC + tid];
    s_d[tid + 257] = desc[b * NC + tid + 256];
    __syncthreads();

    const float w0 = w[0], w1 = w[1], w2 = w[2];
    // cross-correlation (lax conv does NOT flip the kernel)
    const int c0 = tid, c1 = tid + 256;
    const float t0 = s_d[c0] * w0 + s_d[c0 + 1] * w1 + s_d[c0 + 2] * w2;
    const float t1 = s_d[c1] * w0 + s_d[c1 + 1] * w1 + s_d[c1 + 2] * w2;
    const float sc0 = 1.0f / (1.0f + expf(-t0));
    const float sc1 = 1.0f / (1.0f + expf(-t1));
    s_score[c0] = sc0;
    s_score[c1] = sc1;
    __syncthreads();

    // ---- rank-based selection (lax.top_k tie-break: lower index wins) ----
    int rank0 = 0, rank1 = 0;
    for (int j = 0; j < NC; ++j) {
        const float sj = s_score[j];     // LDS broadcast (same j all lanes)
        rank0 += (sj > sc0) || (sj == sc0 && j < c0);
        rank1 += (sj > sc1) || (sj == sc1 && j < c1);
    }
    const int flag0 = (rank0 < KSEL) ? 1 : 0;
    const int flag1 = (rank1 < KSEL) ? 1 : 0;

    // chunk i covers channels [64i,64i+64): chunks 0..3 from flag0 ballots
    // (waves 0..3), chunks 4..7 from flag1 ballots.
    const unsigned long long bal0 = __ballot(flag0);
    const unsigned long long bal1 = __ballot(flag1);
    const int wid = tid >> 6, lane = tid & 63;
    if (lane == 0) {
        s_wcnt[wid]     = __popcll(bal0);
        s_wcnt[wid + 4] = __popcll(bal1);
    }
    __syncthreads();

    const unsigned long long lmask = (1ULL << lane) - 1ULL;
    if (flag0) {
        int pos = __popcll(bal0 & lmask);
        for (int j = 0; j < wid; ++j) pos += s_wcnt[j];
        s_idx[pos] = c0;
        s_sv[pos]  = sc0;
    }
    if (flag1) {
        int pos = __popcll(bal1 & lmask);
        for (int j = 0; j < wid + 4; ++j) pos += s_wcnt[j];
        s_idx[pos] = c1;
        s_sv[pos]  = sc1;
    }
    __syncthreads();

    // ---- gather this block's 8 selected channels ----
    for (int p = 0; p < 8; ++p) {
        const int k  = kbase + p;
        const int ch = s_idx[k];
        const float sv = s_sv[k];

        const f32x4* src = (const f32x4*)(x + ((size_t)b * NC + ch) * HW);
        f32x4*       dst = (f32x4*)(out + ((size_t)b * KSEL + k) * HW);

#pragma unroll
        for (int i = 0; i < 3; ++i) {    // 784 = 3*256 + 16
            f32x4 v = src[tid + i * 256];
            v.x *= sv; v.y *= sv; v.z *= sv; v.w *= sv;
            __builtin_nontemporal_store(v, &dst[tid + i * 256]);
        }
        if (tid < 16) {
            f32x4 v = src[tid + 768];
            v.x *= sv; v.y *= sv; v.z *= sv; v.w *= sv;
            __builtin_nontemporal_store(v, &dst[tid + 768]);
        }
    }
}

extern "C" void kernel_launch(void* const* d_in, const int* in_sizes, int n_in,
                              void* d_out, int out_size, void* d_ws, size_t ws_size,
                              hipStream_t stream)
{
    const float* x = (const float*)d_in[0];   // [32,512,56,56]
    const float* w = (const float*)d_in[1];   // [1,1,3] -> 3 floats
    float* out = (float*)d_out;               // [32,256,56,56]

    float* desc = (float*)d_ws;               // ws: desc[16384] floats

    // Kernel 1: 16384 rows, 2 rows/wave, 4 waves/block -> 2048 blocks
    reduce_mean_max<<<(NB * NC) / 8, 256, 0, stream>>>(x, desc);

    // Kernel 2: fused redundant top-k + gather, 32 blocks/batch
    topk_gather<<<NB * 32, 256, 0, stream>>>(x, w, desc, out);
}